// Round 1
// baseline (959.980 us; speedup 1.0000x reference)
//
#include <hip/hip_runtime.h>
#include <stdint.h>

// Problem constants
#define BATCH 4
#define SEQ   2048
#define DIM_  1024
#define NHEAD 16
#define HDIM  64
#define QKVLD 3072   // row stride of qkv buffer (3*DIM)

typedef __attribute__((ext_vector_type(8))) short bf8;   // 8 bf16 raw bits
typedef __attribute__((ext_vector_type(4))) short s4v;
typedef __attribute__((ext_vector_type(4))) float f4;

#define MFMA(a, b, c) __builtin_amdgcn_mfma_f32_16x16x32_bf16(a, b, c, 0, 0, 0)

static __device__ __forceinline__ short f2b(float f) {
    uint32_t u = __builtin_bit_cast(uint32_t, f);
    u = (u + 0x7FFFu + ((u >> 16) & 1u)) >> 16;   // RNE
    return (short)u;
}

// ---------------------------------------------------------------- cast kernel
__global__ void cvt_f32_bf16(const float* __restrict__ in, short* __restrict__ out, int n4) {
    int i = blockIdx.x * blockDim.x + threadIdx.x;
    if (i < n4) {
        float4 v = ((const float4*)in)[i];
        s4v o;
        o.x = f2b(v.x); o.y = f2b(v.y); o.z = f2b(v.z); o.w = f2b(v.w);
        ((s4v*)out)[i] = o;
    }
}

// ------------------------------------------------------- C = A @ W^T  (MFMA)
// A: [M,K] bf16 row-major. W: [N,K] bf16 row-major. C: [M,N] bf16 or fp32.
// Block: 256 thr = 4 waves. Block tile 64(m) x 64(n); wave w owns rows w*16..+15.
template <int OUTF32>
__global__ __launch_bounds__(256) void gemm_bt(const short* __restrict__ A,
                                               const short* __restrict__ W,
                                               void* __restrict__ Cp,
                                               int M, int N, int K) {
    const int lane = threadIdx.x & 63, wave = threadIdx.x >> 6;
    const int quad = lane >> 4, l16 = lane & 15;
    const int m0 = blockIdx.y * 64 + wave * 16;
    const int n0 = blockIdx.x * 64;

    const short* Ap  = A + (size_t)(m0 + l16) * K + quad * 8;
    const short* Wp0 = W + (size_t)(n0 + l16) * K + quad * 8;
    const short* Wp1 = Wp0 + (size_t)16 * K;
    const short* Wp2 = Wp0 + (size_t)32 * K;
    const short* Wp3 = Wp0 + (size_t)48 * K;

    f4 acc[4] = {};
    #pragma unroll 2
    for (int k = 0; k < K; k += 32) {
        bf8 a  = *(const bf8*)(Ap + k);
        bf8 b0 = *(const bf8*)(Wp0 + k);
        bf8 b1 = *(const bf8*)(Wp1 + k);
        bf8 b2 = *(const bf8*)(Wp2 + k);
        bf8 b3 = *(const bf8*)(Wp3 + k);
        acc[0] = MFMA(a, b0, acc[0]);
        acc[1] = MFMA(a, b1, acc[1]);
        acc[2] = MFMA(a, b2, acc[2]);
        acc[3] = MFMA(a, b3, acc[3]);
    }

    const int row = m0 + quad * 4;   // + r
    #pragma unroll
    for (int nt = 0; nt < 4; ++nt) {
        const int col = n0 + nt * 16 + l16;
        #pragma unroll
        for (int r = 0; r < 4; ++r) {
            if (OUTF32)
                ((float*)Cp)[(size_t)(row + r) * N + col] = acc[nt][r];
            else
                ((short*)Cp)[(size_t)(row + r) * N + col] = f2b(acc[nt][r]);
        }
    }
}

// -------------------------------------------------------------- flash attention
// qkv: [B*L, 3072] bf16 (Q | K | V per row). out: [B*L, 1024] bf16.
// grid: (L/64, B*NHEAD). Block 256 thr = 4 waves; wave owns 16 q-rows.
__global__ __launch_bounds__(256) void flash_attn(const short* __restrict__ qkv,
                                                  short* __restrict__ out) {
    const int bh = blockIdx.y;
    const int b  = bh >> 4;          // / NHEAD
    const int h  = bh & 15;
    const int qt = blockIdx.x;
    const int q0 = qt * 64;
    const int lane = threadIdx.x & 63, wave = threadIdx.x >> 6;
    const int quad = lane >> 4, l16 = lane & 15;

    __shared__ __align__(16) short Vt[64 * 72];        // V transposed [d][key], pad 8
    __shared__ __align__(16) short Pl[4][16 * 72];     // per-wave P tile, pad 8

    const size_t base = (size_t)b * SEQ * QKVLD;

    // Q fragments for this wave's 16 rows (K=64 -> 2 MFMA k-steps), kept in regs.
    const short* qptr = qkv + base + (size_t)(q0 + wave * 16 + l16) * QKVLD + h * 64 + quad * 8;
    const bf8 qa0 = *(const bf8*)(qptr);
    const bf8 qa1 = *(const bf8*)(qptr + 32);

    f4 o[4] = {};
    float m_i[4] = {-1e30f, -1e30f, -1e30f, -1e30f};
    float l_i[4] = {0.f, 0.f, 0.f, 0.f};
    const int rowg = q0 + wave * 16 + quad * 4;   // + r
    const float scale = 0.125f;                   // 1/sqrt(64)

    for (int c = 0; c <= qt; ++c) {
        const int k0 = c * 64;
        __syncthreads();
        // ---- stage V tile transposed: Vt[d][key] ----
        {
            const int key  = threadIdx.x >> 2;
            const int dseg = (threadIdx.x & 3) * 16;
            const short* vp = qkv + base + (size_t)(k0 + key) * QKVLD + 2048 + h * 64 + dseg;
            bf8 v0 = *(const bf8*)vp;
            bf8 v1 = *(const bf8*)(vp + 8);
            #pragma unroll
            for (int i = 0; i < 8; ++i) {
                Vt[(dseg + i) * 72 + key]     = v0[i];
                Vt[(dseg + 8 + i) * 72 + key] = v1[i];
            }
        }
        __syncthreads();

        // ---- S = Q K^T (16x64 per wave) ----
        f4 s[4] = {};
        const short* kp = qkv + base + (size_t)(k0 + l16) * QKVLD + 1024 + h * 64 + quad * 8;
        #pragma unroll
        for (int nt = 0; nt < 4; ++nt) {
            bf8 b0 = *(const bf8*)(kp + (size_t)(nt * 16) * QKVLD);
            bf8 b1 = *(const bf8*)(kp + (size_t)(nt * 16) * QKVLD + 32);
            s[nt] = MFMA(qa0, b0, s[nt]);
            s[nt] = MFMA(qa1, b1, s[nt]);
        }

        // ---- scale + causal mask + row-max ----
        float mx[4] = {-1e30f, -1e30f, -1e30f, -1e30f};
        #pragma unroll
        for (int nt = 0; nt < 4; ++nt) {
            const int colg = k0 + nt * 16 + l16;
            #pragma unroll
            for (int r = 0; r < 4; ++r) {
                float sv = s[nt][r] * scale;
                if (colg > rowg + r) sv = -1e30f;
                s[nt][r] = sv;
                mx[r] = fmaxf(mx[r], sv);
            }
        }
        #pragma unroll
        for (int r = 0; r < 4; ++r) {
            float v = mx[r];
            v = fmaxf(v, __shfl_xor(v, 1));
            v = fmaxf(v, __shfl_xor(v, 2));
            v = fmaxf(v, __shfl_xor(v, 4));
            v = fmaxf(v, __shfl_xor(v, 8));
            mx[r] = v;
        }

        // ---- online softmax update ----
        #pragma unroll
        for (int r = 0; r < 4; ++r) {
            const float mn = fmaxf(m_i[r], mx[r]);
            const float alpha = __expf(m_i[r] - mn);
            m_i[r] = mn;
            float rs = 0.f;
            #pragma unroll
            for (int nt = 0; nt < 4; ++nt) {
                const float pv = __expf(s[nt][r] - mn);
                s[nt][r] = pv;      // s now holds P
                rs += pv;
            }
            rs += __shfl_xor(rs, 1);
            rs += __shfl_xor(rs, 2);
            rs += __shfl_xor(rs, 4);
            rs += __shfl_xor(rs, 8);
            l_i[r] = l_i[r] * alpha + rs;
            o[0][r] *= alpha; o[1][r] *= alpha; o[2][r] *= alpha; o[3][r] *= alpha;
        }

        // ---- P: C-layout regs -> LDS (A-layout source for PV) ----
        #pragma unroll
        for (int nt = 0; nt < 4; ++nt)
            #pragma unroll
            for (int r = 0; r < 4; ++r)
                Pl[wave][(quad * 4 + r) * 72 + nt * 16 + l16] = f2b(s[nt][r]);
        __syncthreads();

        // ---- O += P @ V ----
        const short* pp = &Pl[wave][l16 * 72 + quad * 8];
        const bf8 pa0 = *(const bf8*)(pp);
        const bf8 pa1 = *(const bf8*)(pp + 32);
        #pragma unroll
        for (int nt = 0; nt < 4; ++nt) {
            const short* vtp = &Vt[(nt * 16 + l16) * 72 + quad * 8];
            bf8 b0 = *(const bf8*)(vtp);
            bf8 b1 = *(const bf8*)(vtp + 32);
            o[nt] = MFMA(pa0, b0, o[nt]);
            o[nt] = MFMA(pa1, b1, o[nt]);
        }
    }

    // ---- epilogue: normalize + store ----
    #pragma unroll
    for (int r = 0; r < 4; ++r) {
        const float inv = 1.0f / l_i[r];
        const size_t orow = (size_t)(b * SEQ + rowg + r) * DIM_ + h * 64;
        #pragma unroll
        for (int nt = 0; nt < 4; ++nt)
            out[orow + nt * 16 + l16] = f2b(o[nt][r] * inv);
    }
}

// ----------------------------------------------------------------------------
extern "C" void kernel_launch(void* const* d_in, const int* in_sizes, int n_in,
                              void* d_out, int out_size, void* d_ws, size_t ws_size,
                              hipStream_t stream) {
    const float* x    = (const float*)d_in[0];   // [4,2048,1024]
    const float* wqkv = (const float*)d_in[1];   // [3072,1024]
    const float* wout = (const float*)d_in[2];   // [1024,1024]

    char* ws = (char*)d_ws;
    short* xb    = (short*)(ws);                                   // 16 MB
    short* wqkvb = (short*)(ws + (size_t)(16) * (1 << 20));        //  6 MB
    short* woutb = (short*)(ws + (size_t)(22) * (1 << 20));        //  2 MB
    short* qkvb  = (short*)(ws + (size_t)(24) * (1 << 20));        // 48 MB
    short* attnb = (short*)(ws + (size_t)(72) * (1 << 20));        // 16 MB

    int n4;
    n4 = BATCH * SEQ * DIM_ / 4;
    cvt_f32_bf16<<<(n4 + 255) / 256, 256, 0, stream>>>(x, xb, n4);
    n4 = 3 * DIM_ * DIM_ / 4;
    cvt_f32_bf16<<<(n4 + 255) / 256, 256, 0, stream>>>(wqkv, wqkvb, n4);
    n4 = DIM_ * DIM_ / 4;
    cvt_f32_bf16<<<(n4 + 255) / 256, 256, 0, stream>>>(wout, woutb, n4);

    // qkv = x @ W_qkv^T : [8192, 3072]
    gemm_bt<0><<<dim3(3 * DIM_ / 64, BATCH * SEQ / 64), 256, 0, stream>>>(
        xb, wqkvb, qkvb, BATCH * SEQ, 3 * DIM_, DIM_);

    // flash attention -> attnb [8192, 1024]
    flash_attn<<<dim3(SEQ / 64, BATCH * NHEAD), 256, 0, stream>>>(qkvb, attnb);

    // out = attnb @ W_out^T : [8192, 1024] fp32
    gemm_bt<1><<<dim3(DIM_ / 64, BATCH * SEQ / 64), 256, 0, stream>>>(
        attnb, woutb, d_out, BATCH * SEQ, DIM_, DIM_);
}

// Round 2
// 489.335 us; speedup vs baseline: 1.9618x; 1.9618x over previous
//
#include <hip/hip_runtime.h>
#include <stdint.h>

// Problem constants
#define BATCH 4
#define SEQ   2048
#define DIM_  1024
#define NHEAD 16
#define HDIM  64
#define QKVLD 3072   // row stride of qkv buffer (3*DIM)

typedef __attribute__((ext_vector_type(8))) short bf8;   // 8 bf16 raw bits
typedef __attribute__((ext_vector_type(4))) short s4v;
typedef __attribute__((ext_vector_type(4))) float f4;

#define MFMA(a, b, c) __builtin_amdgcn_mfma_f32_16x16x32_bf16(a, b, c, 0, 0, 0)

static __device__ __forceinline__ short f2b(float f) {
    uint32_t u = __builtin_bit_cast(uint32_t, f);
    u = (u + 0x7FFFu + ((u >> 16) & 1u)) >> 16;   // RNE
    return (short)u;
}

// async global->LDS, 16 bytes per lane. LDS dest is wave-uniform base + lane*16,
// so the LDS layout must be contiguous in lane order (no padding!).
typedef const uint32_t __attribute__((address_space(1)))* gas_t;
typedef uint32_t __attribute__((address_space(3)))* las_t;
static __device__ __forceinline__ void gl_lds16(const short* g, short* l) {
    __builtin_amdgcn_global_load_lds((gas_t)g, (las_t)l, 16, 0, 0);
}

// ---------------------------------------------------------------- cast kernel
__global__ void cvt_f32_bf16(const float* __restrict__ in, short* __restrict__ out, int n4) {
    int i = blockIdx.x * blockDim.x + threadIdx.x;
    if (i < n4) {
        float4 v = ((const float4*)in)[i];
        s4v o;
        o.x = f2b(v.x); o.y = f2b(v.y); o.z = f2b(v.z); o.w = f2b(v.w);
        ((s4v*)out)[i] = o;
    }
}

// ------------------------------------------------- C = A @ W^T  (m97 structure)
// A: [M,K] bf16 row-major. W: [N,K] bf16 row-major. C: [M,N] bf16 or fp32.
// 256 thr = 4 waves in 2x2; block tile 128x128, BK=32.
// LDS tiles [128][32] row-major UNPADDED (global_load_lds lane-order constraint).
template <int OUTF32>
__global__ __launch_bounds__(256) void gemm_bt(const short* __restrict__ A,
                                               const short* __restrict__ W,
                                               void* __restrict__ Cp,
                                               int M, int N, int K) {
    __shared__ __align__(16) short As[128 * 32];
    __shared__ __align__(16) short Bs[128 * 32];

    const int tid  = threadIdx.x;
    const int lane = tid & 63;
    const int wave = tid >> 6;
    const int quad = lane >> 4, l16 = lane & 15;
    const int wr = wave >> 1, wc = wave & 1;      // 2x2 wave grid
    const int m0 = blockIdx.y * 128;
    const int n0 = blockIdx.x * 128;

    // staging: thread t covers row t>>2 (and +64), 16B chunk (t&3)
    const int srow   = tid >> 2;          // 0..63
    const int schunk = (tid & 3) * 8;     // element offset
    const short* Ag0 = A + (size_t)(m0 + srow) * K + schunk;
    const short* Ag1 = Ag0 + (size_t)64 * K;
    const short* Bg0 = W + (size_t)(n0 + srow) * K + schunk;
    const short* Bg1 = Bg0 + (size_t)64 * K;
    short* Al0 = As + srow * 32 + schunk;
    short* Al1 = Al0 + 64 * 32;
    short* Bl0 = Bs + srow * 32 + schunk;
    short* Bl1 = Bl0 + 64 * 32;

    // fragment read pointers (LDS)
    const short* afp = As + (wr * 64 + l16) * 32 + quad * 8;
    const short* bfp = Bs + (wc * 64 + l16) * 32 + quad * 8;

    f4 acc[4][4] = {};

    for (int k0 = 0; k0 < K; k0 += 32) {
        __syncthreads();
        gl_lds16(Ag0 + k0, Al0);
        gl_lds16(Ag1 + k0, Al1);
        gl_lds16(Bg0 + k0, Bl0);
        gl_lds16(Bg1 + k0, Bl1);
        __syncthreads();   // compiler emits vmcnt(0) drain before barrier

        bf8 a[4], b[4];
        #pragma unroll
        for (int i = 0; i < 4; ++i) {
            a[i] = *(const bf8*)(afp + i * 16 * 32);
            b[i] = *(const bf8*)(bfp + i * 16 * 32);
        }
        #pragma unroll
        for (int mt = 0; mt < 4; ++mt)
            #pragma unroll
            for (int nt = 0; nt < 4; ++nt)
                acc[mt][nt] = MFMA(a[mt], b[nt], acc[mt][nt]);
    }

    // epilogue: row = m0+wr*64+mt*16+quad*4+r, col = n0+wc*64+nt*16+l16
    #pragma unroll
    for (int mt = 0; mt < 4; ++mt) {
        const int row = m0 + wr * 64 + mt * 16 + quad * 4;
        #pragma unroll
        for (int nt = 0; nt < 4; ++nt) {
            const int col = n0 + wc * 64 + nt * 16 + l16;
            #pragma unroll
            for (int r = 0; r < 4; ++r) {
                if (OUTF32)
                    ((float*)Cp)[(size_t)(row + r) * N + col] = acc[mt][nt][r];
                else
                    ((short*)Cp)[(size_t)(row + r) * N + col] = f2b(acc[mt][nt][r]);
            }
        }
    }
}

// -------------------------------------------------------------- flash attention
// qkv: [B*L, 3072] bf16 (Q | K | V per row). out: [B*L, 1024] bf16.
// grid: (L/64, B*NHEAD). Block 256 thr = 4 waves; wave owns 16 q-rows.
__global__ __launch_bounds__(256) void flash_attn(const short* __restrict__ qkv,
                                                  short* __restrict__ out) {
    const int bh = blockIdx.y;
    const int b  = bh >> 4;          // / NHEAD
    const int h  = bh & 15;
    const int qt = blockIdx.x;
    const int q0 = qt * 64;
    const int lane = threadIdx.x & 63, wave = threadIdx.x >> 6;
    const int quad = lane >> 4, l16 = lane & 15;

    __shared__ __align__(16) short Vt[64 * 72];        // V transposed [d][key], pad 8
    __shared__ __align__(16) short Pl[4][16 * 72];     // per-wave P tile, pad 8

    const size_t base = (size_t)b * SEQ * QKVLD;

    // Q fragments for this wave's 16 rows (K=64 -> 2 MFMA k-steps), kept in regs.
    const short* qptr = qkv + base + (size_t)(q0 + wave * 16 + l16) * QKVLD + h * 64 + quad * 8;
    const bf8 qa0 = *(const bf8*)(qptr);
    const bf8 qa1 = *(const bf8*)(qptr + 32);

    f4 o[4] = {};
    float m_i[4] = {-1e30f, -1e30f, -1e30f, -1e30f};
    float l_i[4] = {0.f, 0.f, 0.f, 0.f};
    const int rowg = q0 + wave * 16 + quad * 4;   // + r
    const float scale = 0.125f;                   // 1/sqrt(64)

    for (int c = 0; c <= qt; ++c) {
        const int k0 = c * 64;
        __syncthreads();
        // ---- stage V tile transposed: Vt[d][key] ----
        {
            const int key  = threadIdx.x >> 2;
            const int dseg = (threadIdx.x & 3) * 16;
            const short* vp = qkv + base + (size_t)(k0 + key) * QKVLD + 2048 + h * 64 + dseg;
            bf8 v0 = *(const bf8*)vp;
            bf8 v1 = *(const bf8*)(vp + 8);
            #pragma unroll
            for (int i = 0; i < 8; ++i) {
                Vt[(dseg + i) * 72 + key]     = v0[i];
                Vt[(dseg + 8 + i) * 72 + key] = v1[i];
            }
        }
        __syncthreads();

        // ---- S = Q K^T (16x64 per wave) ----
        f4 s[4] = {};
        const short* kp = qkv + base + (size_t)(k0 + l16) * QKVLD + 1024 + h * 64 + quad * 8;
        #pragma unroll
        for (int nt = 0; nt < 4; ++nt) {
            bf8 b0 = *(const bf8*)(kp + (size_t)(nt * 16) * QKVLD);
            bf8 b1 = *(const bf8*)(kp + (size_t)(nt * 16) * QKVLD + 32);
            s[nt] = MFMA(qa0, b0, s[nt]);
            s[nt] = MFMA(qa1, b1, s[nt]);
        }

        // ---- scale + causal mask + row-max ----
        float mx[4] = {-1e30f, -1e30f, -1e30f, -1e30f};
        #pragma unroll
        for (int nt = 0; nt < 4; ++nt) {
            const int colg = k0 + nt * 16 + l16;
            #pragma unroll
            for (int r = 0; r < 4; ++r) {
                float sv = s[nt][r] * scale;
                if (colg > rowg + r) sv = -1e30f;
                s[nt][r] = sv;
                mx[r] = fmaxf(mx[r], sv);
            }
        }
        #pragma unroll
        for (int r = 0; r < 4; ++r) {
            float v = mx[r];
            v = fmaxf(v, __shfl_xor(v, 1));
            v = fmaxf(v, __shfl_xor(v, 2));
            v = fmaxf(v, __shfl_xor(v, 4));
            v = fmaxf(v, __shfl_xor(v, 8));
            mx[r] = v;
        }

        // ---- online softmax update ----
        #pragma unroll
        for (int r = 0; r < 4; ++r) {
            const float mn = fmaxf(m_i[r], mx[r]);
            const float alpha = __expf(m_i[r] - mn);
            m_i[r] = mn;
            float rs = 0.f;
            #pragma unroll
            for (int nt = 0; nt < 4; ++nt) {
                const float pv = __expf(s[nt][r] - mn);
                s[nt][r] = pv;      // s now holds P
                rs += pv;
            }
            rs += __shfl_xor(rs, 1);
            rs += __shfl_xor(rs, 2);
            rs += __shfl_xor(rs, 4);
            rs += __shfl_xor(rs, 8);
            l_i[r] = l_i[r] * alpha + rs;
            o[0][r] *= alpha; o[1][r] *= alpha; o[2][r] *= alpha; o[3][r] *= alpha;
        }

        // ---- P: C-layout regs -> LDS (A-layout source for PV) ----
        #pragma unroll
        for (int nt = 0; nt < 4; ++nt)
            #pragma unroll
            for (int r = 0; r < 4; ++r)
                Pl[wave][(quad * 4 + r) * 72 + nt * 16 + l16] = f2b(s[nt][r]);
        __syncthreads();

        // ---- O += P @ V ----
        const short* pp = &Pl[wave][l16 * 72 + quad * 8];
        const bf8 pa0 = *(const bf8*)(pp);
        const bf8 pa1 = *(const bf8*)(pp + 32);
        #pragma unroll
        for (int nt = 0; nt < 4; ++nt) {
            const short* vtp = &Vt[(nt * 16 + l16) * 72 + quad * 8];
            bf8 b0 = *(const bf8*)(vtp);
            bf8 b1 = *(const bf8*)(vtp + 32);
            o[nt] = MFMA(pa0, b0, o[nt]);
            o[nt] = MFMA(pa1, b1, o[nt]);
        }
    }

    // ---- epilogue: normalize + store ----
    #pragma unroll
    for (int r = 0; r < 4; ++r) {
        const float inv = 1.0f / l_i[r];
        const size_t orow = (size_t)(b * SEQ + rowg + r) * DIM_ + h * 64;
        #pragma unroll
        for (int nt = 0; nt < 4; ++nt)
            out[orow + nt * 16 + l16] = f2b(o[nt][r] * inv);
    }
}

// ----------------------------------------------------------------------------
extern "C" void kernel_launch(void* const* d_in, const int* in_sizes, int n_in,
                              void* d_out, int out_size, void* d_ws, size_t ws_size,
                              hipStream_t stream) {
    const float* x    = (const float*)d_in[0];   // [4,2048,1024]
    const float* wqkv = (const float*)d_in[1];   // [3072,1024]
    const float* wout = (const float*)d_in[2];   // [1024,1024]

    char* ws = (char*)d_ws;
    short* xb    = (short*)(ws);                                   // 16 MB
    short* wqkvb = (short*)(ws + (size_t)(16) * (1 << 20));        //  6 MB
    short* woutb = (short*)(ws + (size_t)(22) * (1 << 20));        //  2 MB
    short* qkvb  = (short*)(ws + (size_t)(24) * (1 << 20));        // 48 MB
    short* attnb = (short*)(ws + (size_t)(72) * (1 << 20));        // 16 MB

    int n4;
    n4 = BATCH * SEQ * DIM_ / 4;
    cvt_f32_bf16<<<(n4 + 255) / 256, 256, 0, stream>>>(x, xb, n4);
    n4 = 3 * DIM_ * DIM_ / 4;
    cvt_f32_bf16<<<(n4 + 255) / 256, 256, 0, stream>>>(wqkv, wqkvb, n4);
    n4 = DIM_ * DIM_ / 4;
    cvt_f32_bf16<<<(n4 + 255) / 256, 256, 0, stream>>>(wout, woutb, n4);

    // qkv = x @ W_qkv^T : [8192, 3072]
    gemm_bt<0><<<dim3(3 * DIM_ / 128, BATCH * SEQ / 128), 256, 0, stream>>>(
        xb, wqkvb, qkvb, BATCH * SEQ, 3 * DIM_, DIM_);

    // flash attention -> attnb [8192, 1024]
    flash_attn<<<dim3(SEQ / 64, BATCH * NHEAD), 256, 0, stream>>>(qkvb, attnb);

    // out = attnb @ W_out^T : [8192, 1024] fp32
    gemm_bt<1><<<dim3(DIM_ / 128, BATCH * SEQ / 128), 256, 0, stream>>>(
        attnb, woutb, d_out, BATCH * SEQ, DIM_, DIM_);
}

// Round 3
// 356.296 us; speedup vs baseline: 2.6943x; 1.3734x over previous
//
#include <hip/hip_runtime.h>
#include <stdint.h>

// Problem constants
#define BATCH 4
#define SEQ   2048
#define DIM_  1024
#define NHEAD 16
#define HDIM  64
#define QKVLD 3072   // row stride of qkv buffer (3*DIM)

typedef __attribute__((ext_vector_type(8))) short bf8;   // 8 bf16 raw bits
typedef __attribute__((ext_vector_type(4))) short s4v;
typedef __attribute__((ext_vector_type(4))) float f4;

#define MFMA(a, b, c) __builtin_amdgcn_mfma_f32_16x16x32_bf16(a, b, c, 0, 0, 0)

static __device__ __forceinline__ short f2b(float f) {
    uint32_t u = __builtin_bit_cast(uint32_t, f);
    u = (u + 0x7FFFu + ((u >> 16) & 1u)) >> 16;   // RNE
    return (short)u;
}

// async global->LDS, 16 bytes per lane. LDS dest is wave-uniform base + lane*16,
// so the LDS layout must be contiguous in lane order (no padding!).
typedef const uint32_t __attribute__((address_space(1)))* gas_t;
typedef uint32_t __attribute__((address_space(3)))* las_t;
static __device__ __forceinline__ void gl_lds16(const short* g, short* l) {
    __builtin_amdgcn_global_load_lds((gas_t)g, (las_t)l, 16, 0, 0);
}

// ---------------------------------------------------------------- cast kernel
__global__ void cvt_f32_bf16(const float* __restrict__ in, short* __restrict__ out, int n4) {
    int i = blockIdx.x * blockDim.x + threadIdx.x;
    if (i < n4) {
        float4 v = ((const float4*)in)[i];
        s4v o;
        o.x = f2b(v.x); o.y = f2b(v.y); o.z = f2b(v.z); o.w = f2b(v.w);
        ((s4v*)out)[i] = o;
    }
}

// ------------------------------------------------- C = A @ W^T  (m97 structure)
template <int OUTF32>
__global__ __launch_bounds__(256) void gemm_bt(const short* __restrict__ A,
                                               const short* __restrict__ W,
                                               void* __restrict__ Cp,
                                               int M, int N, int K) {
    __shared__ __align__(16) short As[128 * 32];
    __shared__ __align__(16) short Bs[128 * 32];

    const int tid  = threadIdx.x;
    const int lane = tid & 63;
    const int wave = tid >> 6;
    const int quad = lane >> 4, l16 = lane & 15;
    const int wr = wave >> 1, wc = wave & 1;
    const int m0 = blockIdx.y * 128;
    const int n0 = blockIdx.x * 128;

    const int srow   = tid >> 2;
    const int schunk = (tid & 3) * 8;
    const short* Ag0 = A + (size_t)(m0 + srow) * K + schunk;
    const short* Ag1 = Ag0 + (size_t)64 * K;
    const short* Bg0 = W + (size_t)(n0 + srow) * K + schunk;
    const short* Bg1 = Bg0 + (size_t)64 * K;
    short* Al0 = As + srow * 32 + schunk;
    short* Al1 = Al0 + 64 * 32;
    short* Bl0 = Bs + srow * 32 + schunk;
    short* Bl1 = Bl0 + 64 * 32;

    const short* afp = As + (wr * 64 + l16) * 32 + quad * 8;
    const short* bfp = Bs + (wc * 64 + l16) * 32 + quad * 8;

    f4 acc[4][4] = {};

    for (int k0 = 0; k0 < K; k0 += 32) {
        __syncthreads();
        gl_lds16(Ag0 + k0, Al0);
        gl_lds16(Ag1 + k0, Al1);
        gl_lds16(Bg0 + k0, Bl0);
        gl_lds16(Bg1 + k0, Bl1);
        __syncthreads();

        bf8 a[4], b[4];
        #pragma unroll
        for (int i = 0; i < 4; ++i) {
            a[i] = *(const bf8*)(afp + i * 16 * 32);
            b[i] = *(const bf8*)(bfp + i * 16 * 32);
        }
        #pragma unroll
        for (int mt = 0; mt < 4; ++mt)
            #pragma unroll
            for (int nt = 0; nt < 4; ++nt)
                acc[mt][nt] = MFMA(a[mt], b[nt], acc[mt][nt]);
    }

    #pragma unroll
    for (int mt = 0; mt < 4; ++mt) {
        const int row = m0 + wr * 64 + mt * 16 + quad * 4;
        #pragma unroll
        for (int nt = 0; nt < 4; ++nt) {
            const int col = n0 + wc * 64 + nt * 16 + l16;
            #pragma unroll
            for (int r = 0; r < 4; ++r) {
                if (OUTF32)
                    ((float*)Cp)[(size_t)(row + r) * N + col] = acc[mt][nt][r];
                else
                    ((short*)Cp)[(size_t)(row + r) * N + col] = f2b(acc[mt][nt][r]);
            }
        }
    }
}

// -------------------------------------------------------------- flash attention
// qkv: [B*L, 3072] bf16 (Q | K | V per row). out: [B*L, 1024] bf16.
// grid: (B*NHEAD, L/64) with qt reversed (longest blocks dispatch first).
// Block 256 thr = 4 waves; wave owns 16 q-rows. Software-pipelined K/V prefetch.
__global__ __launch_bounds__(256) void flash_attn(const short* __restrict__ qkv,
                                                  short* __restrict__ out) {
    const int bh = blockIdx.x;
    const int b  = bh >> 4;
    const int h  = bh & 15;
    const int qt = (gridDim.y - 1) - blockIdx.y;   // longest first
    const int q0 = qt * 64;
    const int tid  = threadIdx.x;
    const int lane = tid & 63, wave = tid >> 6;
    const int quad = lane >> 4, l16 = lane & 15;

    __shared__ __align__(16) short Vt[64 * 72];        // V^T [d][key], pad 8
    __shared__ __align__(16) short Pl[4][16 * 72];     // per-wave P tile, pad 8
    uint32_t* Vt32 = (uint32_t*)Vt;

    const size_t base = (size_t)b * SEQ * QKVLD;

    // Q fragments for this wave's 16 rows (kept in regs).
    const short* qptr = qkv + base + (size_t)(q0 + wave * 16 + l16) * QKVLD + h * 64 + quad * 8;
    const bf8 qa0 = *(const bf8*)(qptr);
    const bf8 qa1 = *(const bf8*)(qptr + 32);

    // V staging assignment: thread t handles key pair kp (keys 2kp,2kp+1), dims dseg..dseg+7
    const int kp   = tid & 31;
    const int dseg = (tid >> 5) * 8;
    const short* vbase = qkv + base + 2048 + h * 64 + dseg;            // + key*QKVLD
    // K fragment base: lane reads row (l16 + nt*16), dims quad*8 + ks*32
    const short* kbase = qkv + base + 1024 + h * 64 + quad * 8 + (size_t)l16 * QKVLD;

    // ---- preload tile 0 ----
    bf8 vr0 = *(const bf8*)(vbase + (size_t)(2 * kp) * QKVLD);
    bf8 vr1 = *(const bf8*)(vbase + (size_t)(2 * kp + 1) * QKVLD);
    bf8 kf[4][2];
    #pragma unroll
    for (int nt = 0; nt < 4; ++nt) {
        kf[nt][0] = *(const bf8*)(kbase + (size_t)(nt * 16) * QKVLD);
        kf[nt][1] = *(const bf8*)(kbase + (size_t)(nt * 16) * QKVLD + 32);
    }

    f4 o[4] = {};
    float m_i[4] = {-1e30f, -1e30f, -1e30f, -1e30f};
    float l_i[4] = {0.f, 0.f, 0.f, 0.f};
    const int rowg = q0 + wave * 16 + quad * 4;   // + r
    const float scale = 0.125f;                   // 1/sqrt(64)

    for (int c = 0; c <= qt; ++c) {
        const int k0 = c * 64;
        __syncthreads();   // previous PV reads of Vt done
        // ---- write V^T tile: packed key-pairs, 2-way banks max ----
        #pragma unroll
        for (int i = 0; i < 8; ++i) {
            uint32_t p = (uint32_t)(uint16_t)vr0[i] | ((uint32_t)(uint16_t)vr1[i] << 16);
            Vt32[(dseg + i) * 36 + kp] = p;
        }
        __syncthreads();   // Vt ready

        // ---- S = Q K^T (16x64 per wave) from prefetched regs ----
        f4 s[4] = {};
        #pragma unroll
        for (int nt = 0; nt < 4; ++nt) {
            s[nt] = MFMA(qa0, kf[nt][0], s[nt]);
            s[nt] = MFMA(qa1, kf[nt][1], s[nt]);
        }

        // ---- prefetch tile c+1 (clamped; junk on last iter, never used) ----
        {
            const int knx = (c < qt) ? (k0 + 64) : k0;
            vr0 = *(const bf8*)(vbase + (size_t)(knx + 2 * kp) * QKVLD);
            vr1 = *(const bf8*)(vbase + (size_t)(knx + 2 * kp + 1) * QKVLD);
            #pragma unroll
            for (int nt = 0; nt < 4; ++nt) {
                kf[nt][0] = *(const bf8*)(kbase + (size_t)(knx + nt * 16) * QKVLD);
                kf[nt][1] = *(const bf8*)(kbase + (size_t)(knx + nt * 16) * QKVLD + 32);
            }
        }

        // ---- scale + (diagonal-only) causal mask + row-max ----
        float mx[4] = {-1e30f, -1e30f, -1e30f, -1e30f};
        if (c == qt) {
            #pragma unroll
            for (int nt = 0; nt < 4; ++nt) {
                const int colg = k0 + nt * 16 + l16;
                #pragma unroll
                for (int r = 0; r < 4; ++r) {
                    float sv = s[nt][r] * scale;
                    if (colg > rowg + r) sv = -1e30f;
                    s[nt][r] = sv;
                    mx[r] = fmaxf(mx[r], sv);
                }
            }
        } else {
            #pragma unroll
            for (int nt = 0; nt < 4; ++nt)
                #pragma unroll
                for (int r = 0; r < 4; ++r) {
                    float sv = s[nt][r] * scale;
                    s[nt][r] = sv;
                    mx[r] = fmaxf(mx[r], sv);
                }
        }
        #pragma unroll
        for (int r = 0; r < 4; ++r) {
            float v = mx[r];
            v = fmaxf(v, __shfl_xor(v, 1));
            v = fmaxf(v, __shfl_xor(v, 2));
            v = fmaxf(v, __shfl_xor(v, 4));
            v = fmaxf(v, __shfl_xor(v, 8));
            mx[r] = v;
        }

        // ---- online softmax update ----
        #pragma unroll
        for (int r = 0; r < 4; ++r) {
            const float mn = fmaxf(m_i[r], mx[r]);
            const float alpha = __expf(m_i[r] - mn);
            m_i[r] = mn;
            float rs = 0.f;
            #pragma unroll
            for (int nt = 0; nt < 4; ++nt) {
                const float pv = __expf(s[nt][r] - mn);
                s[nt][r] = pv;
                rs += pv;
            }
            rs += __shfl_xor(rs, 1);
            rs += __shfl_xor(rs, 2);
            rs += __shfl_xor(rs, 4);
            rs += __shfl_xor(rs, 8);
            l_i[r] = l_i[r] * alpha + rs;
            o[0][r] *= alpha; o[1][r] *= alpha; o[2][r] *= alpha; o[3][r] *= alpha;
        }

        // ---- P: C-layout regs -> per-wave LDS (A-layout). Same-wave RAW:
        // no barrier needed, compiler inserts lgkmcnt wait. ----
        #pragma unroll
        for (int nt = 0; nt < 4; ++nt)
            #pragma unroll
            for (int r = 0; r < 4; ++r)
                Pl[wave][(quad * 4 + r) * 72 + nt * 16 + l16] = f2b(s[nt][r]);

        // ---- O += P @ V ----
        const short* pp = &Pl[wave][l16 * 72 + quad * 8];
        const bf8 pa0 = *(const bf8*)(pp);
        const bf8 pa1 = *(const bf8*)(pp + 32);
        #pragma unroll
        for (int nt = 0; nt < 4; ++nt) {
            const short* vtp = &Vt[(nt * 16 + l16) * 72 + quad * 8];
            bf8 b0 = *(const bf8*)(vtp);
            bf8 b1 = *(const bf8*)(vtp + 32);
            o[nt] = MFMA(pa0, b0, o[nt]);
            o[nt] = MFMA(pa1, b1, o[nt]);
        }
    }

    // ---- epilogue: normalize + store ----
    #pragma unroll
    for (int r = 0; r < 4; ++r) {
        const float inv = 1.0f / l_i[r];
        const size_t orow = (size_t)(b * SEQ + rowg + r) * DIM_ + h * 64;
        #pragma unroll
        for (int nt = 0; nt < 4; ++nt)
            out[orow + nt * 16 + l16] = f2b(o[nt][r] * inv);
    }
}

// ----------------------------------------------------------------------------
extern "C" void kernel_launch(void* const* d_in, const int* in_sizes, int n_in,
                              void* d_out, int out_size, void* d_ws, size_t ws_size,
                              hipStream_t stream) {
    const float* x    = (const float*)d_in[0];   // [4,2048,1024]
    const float* wqkv = (const float*)d_in[1];   // [3072,1024]
    const float* wout = (const float*)d_in[2];   // [1024,1024]

    char* ws = (char*)d_ws;
    short* xb    = (short*)(ws);                                   // 16 MB
    short* wqkvb = (short*)(ws + (size_t)(16) * (1 << 20));        //  6 MB
    short* woutb = (short*)(ws + (size_t)(22) * (1 << 20));        //  2 MB
    short* qkvb  = (short*)(ws + (size_t)(24) * (1 << 20));        // 48 MB
    short* attnb = (short*)(ws + (size_t)(72) * (1 << 20));        // 16 MB

    int n4;
    n4 = BATCH * SEQ * DIM_ / 4;
    cvt_f32_bf16<<<(n4 + 255) / 256, 256, 0, stream>>>(x, xb, n4);
    n4 = 3 * DIM_ * DIM_ / 4;
    cvt_f32_bf16<<<(n4 + 255) / 256, 256, 0, stream>>>(wqkv, wqkvb, n4);
    n4 = DIM_ * DIM_ / 4;
    cvt_f32_bf16<<<(n4 + 255) / 256, 256, 0, stream>>>(wout, woutb, n4);

    // qkv = x @ W_qkv^T : [8192, 3072]
    gemm_bt<0><<<dim3(3 * DIM_ / 128, BATCH * SEQ / 128), 256, 0, stream>>>(
        xb, wqkvb, qkvb, BATCH * SEQ, 3 * DIM_, DIM_);

    // flash attention -> attnb [8192, 1024]
    flash_attn<<<dim3(BATCH * NHEAD, SEQ / 64), 256, 0, stream>>>(qkvb, attnb);

    // out = attnb @ W_out^T : [8192, 1024] fp32
    gemm_bt<1><<<dim3(DIM_ / 128, BATCH * SEQ / 128), 256, 0, stream>>>(
        attnb, woutb, d_out, BATCH * SEQ, DIM_, DIM_);
}